// Round 9
// baseline (177.703 us; speedup 1.0000x reference)
//
#include <hip/hip_runtime.h>
#include <stdint.h>

// NeRF segmented cumprod — FUSED single-pass, STRIPED, SIGN-ENCODED state,
// CONCURRENCY-MAXIMIZED: CHUNK 2048 (NJ=2), 8192 blocks, launch_bounds
// (256,8) => VGPR<=64 => 8 waves/SIMD residency; short per-wave serial
// chain. Round-8 post-mortem: all pipes idle at 67us => wave-slot ILP is
// the limiter, so double residency and halve the chain.
//
// Sign-encoding: x = f ? -v : v  (all v > 0).
//   comb(a,b) = (bits(b)<0) ? b : a*b   == (fb ? vb : va*vb, fa|fb)
// Block prefix via per-wave-redundant backward-window scan (avg seg len 256;
// g=0 always a reset => terminates). One __syncthreads total.

#define BLOCK 256
#define NWAVE (BLOCK / 64)
#define NJ 2
#define WELEM (64 * 4 * NJ)      // 512 elements per wave
#define CHUNK (NWAVE * WELEM)    // 2048 elements per block
#define WIN 256                  // backward-window elements per iteration

__device__ __forceinline__ float comb(float a, float b) {
    return (__float_as_int(b) < 0) ? b : a * b;
}

// alphainv default = cumprod[0] = (1-alpha[0])+1e-11 (ref: last_idx=0 for
// empty rays). Separate dispatch BEFORE fused kernel => ordered, no race.
__global__ void nerf_init(const float* __restrict__ alpha,
                          float* __restrict__ alphainv, int N_ray) {
    int i = blockIdx.x * blockDim.x + threadIdx.x;
    if (i < N_ray) alphainv[i] = (1.0f - alpha[0]) + 1e-11f;
}

__global__ __launch_bounds__(BLOCK, 8)
void nerf_fused(const float* __restrict__ alpha, const int* __restrict__ ray_id,
                float* __restrict__ weights, float* __restrict__ alphainv, int n) {
    __shared__ float s_wv[NWAVE];

    const int c = blockIdx.x, t = threadIdx.x;
    const int lane = t & 63, w = t >> 6;
    const int bstart = c * CHUNK;                 // < 2^25, int-safe
    const int wbase  = bstart + w * WELEM;

    // ---- window iter-0 loads first (head of critical path) ----
    int wlo = bstart - WIN;
    float4 wav; int4 wrv;
    if (c > 0) {
        wav = *(const float4*)(alpha  + wlo + lane * 4);
        wrv = *(const int4*)  (ray_id + wlo + lane * 4);
    }

    // ---- payload loads ----
    float4 A[NJ]; int4 R[NJ];
    #pragma unroll
    for (int j = 0; j < NJ; ++j) {
        const int e0 = wbase + j * 256 + lane * 4;
        if (e0 + 4 <= n) {
            A[j] = *(const float4*)(alpha  + e0);
            R[j] = *(const int4*)  (ray_id + e0);
        } else {
            float aa[4]; int rr[4];
            #pragma unroll
            for (int k = 0; k < 4; ++k) {
                int g = e0 + k;
                aa[k] = (g < n) ? alpha[g]  : 0.0f;
                rr[k] = (g < n) ? ray_id[g] : -2;
            }
            A[j] = make_float4(aa[0], aa[1], aa[2], aa[3]);
            R[j] = make_int4(rr[0], rr[1], rr[2], rr[3]);
        }
    }
    int last_r = -1;
    if (wbase > 0 && wbase - 1 < n) last_r = ray_id[wbase - 1];

    // ---- Phase 1: block prefix P0, per-wave redundant, zero barriers ----
    float P0 = 1.0f;
    if (c > 0) {
        float chain = 1.0f;
        for (;;) {
            int pw = __shfl_up(wrv.w, 1);
            if (lane == 0) pw = (wlo > 0) ? ray_id[wlo - 1] : -1;
            const float om0 = (1.0f - wav.x) + 1e-11f;
            const float om1 = (1.0f - wav.y) + 1e-11f;
            const float om2 = (1.0f - wav.z) + 1e-11f;
            const float om3 = (1.0f - wav.w) + 1e-11f;
            const float s0 = (wrv.x != pw)    ? -om0 : om0;
            const float s1 = (wrv.y != wrv.x) ? -om1 : om1;
            const float s2 = (wrv.z != wrv.y) ? -om2 : om2;
            const float s3 = (wrv.w != wrv.z) ? -om3 : om3;
            float l = comb(comb(comb(s0, s1), s2), s3);
            #pragma unroll
            for (int off = 1; off < 64; off <<= 1) {
                float o = __shfl_down(l, off);
                l = comb(l, o);
            }
            float wagg = __shfl(l, 0);
            chain = comb(wagg, chain);                 // earlier (+) later
            if (__float_as_int(chain) < 0 || wlo == 0) break;
            wlo -= WIN;
            wav = *(const float4*)(alpha  + wlo + lane * 4);
            wrv = *(const int4*)  (ray_id + wlo + lane * 4);
        }
        P0 = chain;
    }

    // ---- Phase 2: per-j wave scans (1 shuffle per step) ----
    float E[NJ]; int PR0[NJ];
    float wrun = 1.0f;
    #pragma unroll
    for (int j = 0; j < NJ; ++j) {
        const int e0 = wbase + j * 256 + lane * 4;
        const float4 av = A[j]; const int4 rv = R[j];
        const bool b0 = e0 < n, b1 = e0 + 1 < n, b2 = e0 + 2 < n, b3 = e0 + 3 < n;
        const float om0 = b0 ? (1.0f - av.x) + 1e-11f : 1.0f;
        const float om1 = b1 ? (1.0f - av.y) + 1e-11f : 1.0f;
        const float om2 = b2 ? (1.0f - av.z) + 1e-11f : 1.0f;
        const float om3 = b3 ? (1.0f - av.w) + 1e-11f : 1.0f;
        int pw = __shfl_up(rv.w, 1);
        const int prev0 = (lane == 0) ? last_r : pw;
        PR0[j] = prev0;
        const float s0 = (b0 && rv.x != prev0) ? -om0 : om0;
        const float s1 = (b1 && rv.y != rv.x)  ? -om1 : om1;
        const float s2 = (b2 && rv.z != rv.y)  ? -om2 : om2;
        const float s3 = (b3 && rv.w != rv.z)  ? -om3 : om3;
        float l = comb(comb(comb(s0, s1), s2), s3);

        float ws = l;
        #pragma unroll
        for (int off = 1; off < 64; off <<= 1) {
            float o = __shfl_up(ws, off);
            if (lane >= off) ws = comb(o, ws);
        }
        float wse = __shfl_up(ws, 1);
        if (lane == 0) wse = 1.0f;
        E[j] = comb(wrun, wse);
        wrun = comb(wrun, __shfl(ws, 63));
        last_r = __shfl(rv.w, 63);
    }

    if (lane == 0) s_wv[w] = wrun;
    __syncthreads();                                    // the ONLY barrier

    float base = P0;
    for (int ww = 0; ww < w; ++ww) base = comb(base, s_wv[ww]);

    // ---- Phase 3: apply + stores. Seg-START scatter: at each flag (g>0),
    // alphainv[ray_id[g-1]] = cumprod[g-1]; global last element writes
    // alphainv[ray_id[n-1]] = cumprod[n-1]. ----
    #pragma unroll
    for (int j = 0; j < NJ; ++j) {
        float P = comb(base, E[j]);
        const float4 av = A[j]; const int4 rv = R[j];
        const int e0 = wbase + j * 256 + lane * 4;
        const bool b0 = e0 < n, b1 = e0 + 1 < n, b2 = e0 + 2 < n, b3 = e0 + 3 < n;
        const float om0 = b0 ? (1.0f - av.x) + 1e-11f : 1.0f;
        const float om1 = b1 ? (1.0f - av.y) + 1e-11f : 1.0f;
        const float om2 = b2 ? (1.0f - av.z) + 1e-11f : 1.0f;
        const float om3 = b3 ? (1.0f - av.w) + 1e-11f : 1.0f;
        const int prev0 = PR0[j];
        const int f0 = b0 && (rv.x != prev0);
        const int f1 = b1 && (rv.y != rv.x);
        const int f2 = b2 && (rv.z != rv.y);
        const int f3 = b3 && (rv.w != rv.z);

        float w0, w1, w2, w3, trans;
        trans = fabsf(P);
        w0 = av.x * trans;
        if (f0 && e0 > 0) alphainv[prev0] = trans;
        P = comb(P, f0 ? -om0 : om0);
        if (b0 && e0 == n - 1) alphainv[rv.x] = fabsf(P);

        trans = fabsf(P);
        w1 = av.y * trans;
        if (f1) alphainv[rv.x] = trans;
        P = comb(P, f1 ? -om1 : om1);
        if (b1 && e0 + 1 == n - 1) alphainv[rv.y] = fabsf(P);

        trans = fabsf(P);
        w2 = av.z * trans;
        if (f2) alphainv[rv.y] = trans;
        P = comb(P, f2 ? -om2 : om2);
        if (b2 && e0 + 2 == n - 1) alphainv[rv.z] = fabsf(P);

        trans = fabsf(P);
        w3 = av.w * trans;
        if (f3) alphainv[rv.z] = trans;
        P = comb(P, f3 ? -om3 : om3);
        if (b3 && e0 + 3 == n - 1) alphainv[rv.w] = fabsf(P);

        if (e0 + 4 <= n) {
            *(float4*)(weights + e0) = make_float4(w0, w1, w2, w3);
        } else {
            float ww4[4] = {w0, w1, w2, w3};
            for (int k = 0; k < 4; ++k) {
                int g = e0 + k;
                if (g < n) weights[g] = ww4[k];
            }
        }
    }
}

extern "C" void kernel_launch(void* const* d_in, const int* in_sizes, int n_in,
                              void* d_out, int out_size, void* d_ws, size_t ws_size,
                              hipStream_t stream) {
    const float* alpha  = (const float*)d_in[0];
    const int*   ray_id = (const int*)d_in[1];
    const int n     = in_sizes[0];
    const int N_ray = out_size - n;          // avoids device read of d_in[2]

    float* weights  = (float*)d_out;
    float* alphainv = weights + n;

    const int nchunks = (n + CHUNK - 1) / CHUNK;

    nerf_init<<<(N_ray + BLOCK - 1) / BLOCK, BLOCK, 0, stream>>>(alpha, alphainv, N_ray);
    nerf_fused<<<nchunks, BLOCK, 0, stream>>>(alpha, ray_id, weights, alphainv, n);
}